// Round 1
// baseline (1591.927 us; speedup 1.0000x reference)
//
#include <hip/hip_runtime.h>
#include <hip/hip_bf16.h>

#define B_ 256
#define S_ 512
#define H_ 512
#define E_ 128
#define V_ 30000
#define RNNIN_ 641

using bf16x8 = __attribute__((ext_vector_type(8))) short;
using f32x4  = __attribute__((ext_vector_type(4))) float;

// fp32 -> bf16 round-to-nearest-even (inputs are finite; no NaN handling needed)
__device__ __forceinline__ short f2bf(float f) {
  unsigned int u = __float_as_uint(f);
  u += 0x7fffu + ((u >> 16) & 1u);
  return (short)(u >> 16);
}

__device__ __forceinline__ float fast_tanh(float x) {
  x = fminf(10.f, fmaxf(-10.f, x));
  float t = __expf(2.f * x);
  return (t - 1.f) / (t + 1.f);
}

__device__ __forceinline__ float sigmoidf(float x) {
  return 1.f / (1.f + __expf(-x));
}

// ---------------------------------------------------------------------------
// Generic small fp32 GEMM: C[m,n] = act(sum_k A[m,k] * B(k,n) + bias[n])
// BT=false: B is (K,N) row-major.  BT=true: B is (N,K) row-major (B transposed).
// 64x64 tile, BK=16, 256 threads, 4x4 micro-tile.
// ---------------------------------------------------------------------------
template<bool BT, bool RELU>
__global__ __launch_bounds__(256) void gemm_f32(
    const float* __restrict__ A, const float* __restrict__ Bm,
    const float* __restrict__ bias, float* __restrict__ C,
    int M, int N, int K)
{
  __shared__ float As[16][65];
  __shared__ float Bs[16][65];
  const int m0 = blockIdx.x * 64, n0 = blockIdx.y * 64;
  const int tid = threadIdx.x;
  const int tx = tid & 15, ty = tid >> 4;
  float acc[4][4] = {};
  for (int k0 = 0; k0 < K; k0 += 16) {
    __syncthreads();
    #pragma unroll
    for (int i = 0; i < 4; i++) {
      int e = tid + i * 256;
      int m = e >> 4, k = e & 15;
      float v = 0.f;
      if (m0 + m < M && k0 + k < K) v = A[(size_t)(m0 + m) * K + k0 + k];
      As[k][m] = v;
    }
    #pragma unroll
    for (int i = 0; i < 4; i++) {
      int e = tid + i * 256;
      if (BT) {
        int n = e >> 4, k = e & 15;
        float v = 0.f;
        if (n0 + n < N && k0 + k < K) v = Bm[(size_t)(n0 + n) * K + k0 + k];
        Bs[k][n] = v;
      } else {
        int k = e >> 6, n = e & 63;
        float v = 0.f;
        if (n0 + n < N && k0 + k < K) v = Bm[(size_t)(k0 + k) * N + n0 + n];
        Bs[k][n] = v;
      }
    }
    __syncthreads();
    #pragma unroll
    for (int k = 0; k < 16; k++) {
      float a[4], b[4];
      #pragma unroll
      for (int i = 0; i < 4; i++) a[i] = As[k][ty * 4 + i];
      #pragma unroll
      for (int j = 0; j < 4; j++) b[j] = Bs[k][tx * 4 + j];
      #pragma unroll
      for (int i = 0; i < 4; i++)
        #pragma unroll
        for (int j = 0; j < 4; j++) acc[i][j] += a[i] * b[j];
    }
  }
  #pragma unroll
  for (int i = 0; i < 4; i++) {
    int m = m0 + ty * 4 + i;
    if (m >= M) continue;
    #pragma unroll
    for (int j = 0; j < 4; j++) {
      int n = n0 + tx * 4 + j;
      if (n >= N) continue;
      float v = acc[i][j] + (bias ? bias[n] : 0.f);
      if (RELU) v = fmaxf(v, 0.f);
      C[(size_t)m * N + n] = v;
    }
  }
}

// ---------------------------------------------------------------------------
// Attention GEMM fused with tanh(.)·v_w row-reduction into scores.
// A = encoder_outputs viewed as (S*B, H) fp32; Bw = attn_w[H:] (H,H) fp32.
// scores[b,s] += sum_n tanh(A·Bw + hid_pb[b,n]) * v_w[n]   (atomic, pre-zeroed)
// Tile 64x256, BK=32, 4 waves side by side in n. bf16 MFMA 16x16x32.
// ---------------------------------------------------------------------------
__global__ __launch_bounds__(256) void attn_gemm_score(
    const float* __restrict__ A, const float* __restrict__ Bw,
    const float* __restrict__ hid_pb, const float* __restrict__ v_w,
    float* __restrict__ scores)
{
  constexpr int LDP = 40;  // padded bf16 row length (BK=32 + 8)
  __shared__ short As[64 * LDP];
  __shared__ short Bs[256 * LDP];
  const int n0 = blockIdx.x * 256;  // n-tile fastest: the 2 n-tiles of one m-tile co-run
  const int m0 = blockIdx.y * 64;
  const int tid = threadIdx.x;
  const int lane = tid & 63;
  const int wv = tid >> 6;             // wave 0..3 -> n-quadrant
  const int quad = lane >> 4, l15 = lane & 15;

  f32x4 acc[4][4];
  #pragma unroll
  for (int i = 0; i < 4; i++)
    #pragma unroll
    for (int j = 0; j < 4; j++) acc[i][j] = f32x4{0.f, 0.f, 0.f, 0.f};

  for (int k0 = 0; k0 < H_; k0 += 32) {
    __syncthreads();
    // A tile: 64 rows x 32 k (fp32 -> bf16)
    #pragma unroll
    for (int i = 0; i < 2; i++) {
      int idx = tid + 256 * i;
      int m = idx >> 3, kg = idx & 7;
      float4 v = *(const float4*)(A + (size_t)(m0 + m) * H_ + k0 + kg * 4);
      short4 sv; sv.x = f2bf(v.x); sv.y = f2bf(v.y); sv.z = f2bf(v.z); sv.w = f2bf(v.w);
      *(short4*)(As + m * LDP + kg * 4) = sv;
    }
    // B tile: 32 k x 256 n, stored transposed Bs[n][k]
    #pragma unroll
    for (int i = 0; i < 8; i++) {
      int idx = tid + 256 * i;
      int kk = idx >> 6, g = idx & 63;
      float4 v = *(const float4*)(Bw + (size_t)(k0 + kk) * H_ + n0 + g * 4);
      Bs[(g * 4 + 0) * LDP + kk] = f2bf(v.x);
      Bs[(g * 4 + 1) * LDP + kk] = f2bf(v.y);
      Bs[(g * 4 + 2) * LDP + kk] = f2bf(v.z);
      Bs[(g * 4 + 3) * LDP + kk] = f2bf(v.w);
    }
    __syncthreads();
    bf16x8 af[4], bfr[4];
    #pragma unroll
    for (int ti = 0; ti < 4; ti++)
      af[ti] = *(const bf16x8*)(As + (ti * 16 + l15) * LDP + quad * 8);
    #pragma unroll
    for (int tj = 0; tj < 4; tj++)
      bfr[tj] = *(const bf16x8*)(Bs + (wv * 64 + tj * 16 + l15) * LDP + quad * 8);
    #pragma unroll
    for (int ti = 0; ti < 4; ti++)
      #pragma unroll
      for (int tj = 0; tj < 4; tj++)
        acc[ti][tj] = __builtin_amdgcn_mfma_f32_16x16x32_bf16(af[ti], bfr[tj], acc[ti][tj], 0, 0, 0);
  }

  // Epilogue: D row=(quad*4+r), col=l15 within each 16x16 tile (m89-verified layout)
  #pragma unroll
  for (int ti = 0; ti < 4; ti++) {
    #pragma unroll
    for (int r = 0; r < 4; r++) {
      int m = m0 + ti * 16 + quad * 4 + r;   // row index into (S*B)
      int b = m & (B_ - 1);
      int s = m >> 8;
      float sum = 0.f;
      #pragma unroll
      for (int tj = 0; tj < 4; tj++) {
        int n = n0 + wv * 64 + tj * 16 + l15;
        float v = acc[ti][tj][r] + hid_pb[b * H_ + n];
        sum += fast_tanh(v) * v_w[n];
      }
      sum += __shfl_xor(sum, 1);
      sum += __shfl_xor(sum, 2);
      sum += __shfl_xor(sum, 4);
      sum += __shfl_xor(sum, 8);
      if (l15 == 0) atomicAdd(scores + b * S_ + s, sum);
    }
  }
}

// ---------------------------------------------------------------------------
// Logits GEMM: C(256,30000) = h1(256,512) @ fc_id_w(512,30000) + fc_id_b
// Tile 256x64 (single m-tile: fc_id_w read exactly once), BK=32, waves stacked in m.
// ---------------------------------------------------------------------------
__global__ __launch_bounds__(256) void logits_gemm(
    const float* __restrict__ A, const float* __restrict__ Bw,
    const float* __restrict__ bias, float* __restrict__ C)
{
  constexpr int LDP = 40;
  __shared__ short As[256 * LDP];
  __shared__ short Bs[64 * LDP];
  const int n0 = blockIdx.x * 64;
  const int tid = threadIdx.x;
  const int lane = tid & 63;
  const int wv = tid >> 6;             // wave -> m-quadrant
  const int quad = lane >> 4, l15 = lane & 15;

  f32x4 acc[4][4];
  #pragma unroll
  for (int i = 0; i < 4; i++)
    #pragma unroll
    for (int j = 0; j < 4; j++) acc[i][j] = f32x4{0.f, 0.f, 0.f, 0.f};

  for (int k0 = 0; k0 < H_; k0 += 32) {
    __syncthreads();
    #pragma unroll
    for (int i = 0; i < 8; i++) {
      int idx = tid + 256 * i;
      int m = idx >> 3, kg = idx & 7;
      float4 v = *(const float4*)(A + (size_t)m * H_ + k0 + kg * 4);
      short4 sv; sv.x = f2bf(v.x); sv.y = f2bf(v.y); sv.z = f2bf(v.z); sv.w = f2bf(v.w);
      *(short4*)(As + m * LDP + kg * 4) = sv;
    }
    #pragma unroll
    for (int i = 0; i < 2; i++) {
      int idx = tid + 256 * i;
      int kk = idx >> 4, g = idx & 15;
      int n = n0 + g * 4;
      float4 v = make_float4(0.f, 0.f, 0.f, 0.f);
      if (n < V_) v = *(const float4*)(Bw + (size_t)(k0 + kk) * V_ + n);
      Bs[(g * 4 + 0) * LDP + kk] = f2bf(v.x);
      Bs[(g * 4 + 1) * LDP + kk] = f2bf(v.y);
      Bs[(g * 4 + 2) * LDP + kk] = f2bf(v.z);
      Bs[(g * 4 + 3) * LDP + kk] = f2bf(v.w);
    }
    __syncthreads();
    bf16x8 af[4], bfr[4];
    #pragma unroll
    for (int ti = 0; ti < 4; ti++)
      af[ti] = *(const bf16x8*)(As + (wv * 64 + ti * 16 + l15) * LDP + quad * 8);
    #pragma unroll
    for (int tj = 0; tj < 4; tj++)
      bfr[tj] = *(const bf16x8*)(Bs + (tj * 16 + l15) * LDP + quad * 8);
    #pragma unroll
    for (int ti = 0; ti < 4; ti++)
      #pragma unroll
      for (int tj = 0; tj < 4; tj++)
        acc[ti][tj] = __builtin_amdgcn_mfma_f32_16x16x32_bf16(af[ti], bfr[tj], acc[ti][tj], 0, 0, 0);
  }
  #pragma unroll
  for (int ti = 0; ti < 4; ti++)
    #pragma unroll
    for (int r = 0; r < 4; r++) {
      int m = wv * 64 + ti * 16 + quad * 4 + r;
      #pragma unroll
      for (int tj = 0; tj < 4; tj++) {
        int n = n0 + tj * 16 + l15;
        if (n < V_) C[(size_t)m * V_ + n] = acc[ti][tj][r] + bias[n];
      }
    }
}

// --------------------------- small kernels ---------------------------------
__global__ __launch_bounds__(256) void attn_softmax(
    const float* __restrict__ scores, const int* __restrict__ mask, float* __restrict__ aw)
{
  int b = blockIdx.x, tid = threadIdx.x;
  __shared__ float red[256];
  float v0 = scores[b * S_ + tid];
  float v1 = scores[b * S_ + tid + 256];
  if (mask[b * S_ + tid] == 0) v0 = -1e10f;
  if (mask[b * S_ + tid + 256] == 0) v1 = -1e10f;
  red[tid] = fmaxf(v0, v1);
  __syncthreads();
  for (int off = 128; off; off >>= 1) { if (tid < off) red[tid] = fmaxf(red[tid], red[tid + off]); __syncthreads(); }
  float mx = red[0];
  __syncthreads();
  float e0 = __expf(v0 - mx), e1 = __expf(v1 - mx);
  red[tid] = e0 + e1;
  __syncthreads();
  for (int off = 128; off; off >>= 1) { if (tid < off) red[tid] += red[tid + off]; __syncthreads(); }
  float inv = 1.f / red[0];
  aw[b * S_ + tid] = e0 * inv;
  aw[b * S_ + tid + 256] = e1 * inv;
}

__global__ __launch_bounds__(512) void attn_weighted(
    const float* __restrict__ aw, const float* __restrict__ enc, float* __restrict__ weighted)
{
  int b = blockIdx.x, h = threadIdx.x;
  __shared__ float a_s[S_];
  a_s[h] = aw[b * S_ + h];
  __syncthreads();
  float acc = 0.f;
  #pragma unroll 8
  for (int s = 0; s < S_; s++)
    acc += a_s[s] * enc[((size_t)s * B_ + b) * H_ + h];
  weighted[b * H_ + h] = acc;
}

__global__ void build_x(const float* __restrict__ weighted, const int* __restrict__ ids,
                        const float* __restrict__ emb, const float* __restrict__ rate,
                        float* __restrict__ x)
{
  int i = blockIdx.x * 256 + threadIdx.x;
  if (i >= B_ * RNNIN_) return;
  int b = i / RNNIN_, j = i % RNNIN_;
  float v;
  if (j < H_) v = weighted[b * H_ + j];
  else if (j < H_ + E_) v = emb[(size_t)ids[b] * E_ + (j - H_)];
  else v = rate[b];
  x[i] = v;
}

__global__ void gru_gates(const float* __restrict__ gi, const float* __restrict__ gh,
                          const float* __restrict__ h0, float* __restrict__ h1,
                          float* __restrict__ h1_out)
{
  int i = blockIdx.x * 256 + threadIdx.x;  // B*H
  int b = i >> 9, j = i & (H_ - 1);
  const float* gib = gi + (size_t)b * 1536;
  const float* ghb = gh + (size_t)b * 1536;
  float r = sigmoidf(gib[j] + ghb[j]);
  float z = sigmoidf(gib[512 + j] + ghb[512 + j]);
  float n = fast_tanh(gib[1024 + j] + r * ghb[1024 + j]);
  float h = (1.f - z) * n + z * h0[i];
  h1[i] = h;
  h1_out[i] = h;
}

__global__ __launch_bounds__(256) void row_max(const float* __restrict__ logits, float* __restrict__ rowmax)
{
  int b = blockIdx.x, tid = threadIdx.x;
  float mx = -INFINITY;
  for (int v = tid; v < V_; v += 256) mx = fmaxf(mx, logits[(size_t)b * V_ + v]);
  __shared__ float red[256];
  red[tid] = mx;
  __syncthreads();
  for (int off = 128; off; off >>= 1) { if (tid < off) red[tid] = fmaxf(red[tid], red[tid + off]); __syncthreads(); }
  if (tid == 0) rowmax[b] = red[0];
}

__global__ __launch_bounds__(256) void exp_cv_sum(float* __restrict__ eb, const float* __restrict__ cv,
                                                  const float* __restrict__ rowmax, float* __restrict__ Z)
{
  int b = blockIdx.x, tid = threadIdx.x;
  float m = rowmax[b], s = 0.f;
  for (int v = tid; v < V_; v += 256) {
    size_t idx = (size_t)b * V_ + v;
    float e = __expf(eb[idx] - m) * cv[idx];
    eb[idx] = e;
    s += e;
  }
  __shared__ float red[256];
  red[tid] = s;
  __syncthreads();
  for (int off = 128; off; off >>= 1) { if (tid < off) red[tid] += red[tid + off]; __syncthreads(); }
  if (tid == 0) Z[b] = red[0];
}

__global__ void norm_log(float* __restrict__ e, const float* __restrict__ Z)
{
  int b = blockIdx.y;
  int v = blockIdx.x * 256 + threadIdx.x;
  if (v >= V_) return;
  size_t i = (size_t)b * V_ + v;
  float p = e[i] / Z[b];
  p = fminf(fmaxf(p, 1e-6f), 1.0f);
  e[i] = __logf(p);
}

__global__ __launch_bounds__(256) void row_argmax(const float* __restrict__ pred, int* __restrict__ maxid)
{
  int b = blockIdx.x, tid = threadIdx.x;
  float best = -INFINITY;
  int bi = 0;
  for (int v = tid; v < V_; v += 256) {
    float x = pred[(size_t)b * V_ + v];
    if (x > best) { best = x; bi = v; }
  }
  __shared__ float rv[256];
  __shared__ int ri[256];
  rv[tid] = best; ri[tid] = bi;
  __syncthreads();
  for (int off = 128; off; off >>= 1) {
    if (tid < off) {
      if (rv[tid + off] > rv[tid] || (rv[tid + off] == rv[tid] && ri[tid + off] < ri[tid])) {
        rv[tid] = rv[tid + off]; ri[tid] = ri[tid + off];
      }
    }
    __syncthreads();
  }
  if (tid == 0) maxid[b] = ri[0];
}

__global__ void build_tandem(const int* __restrict__ maxid, const float* __restrict__ emb,
                             const float* __restrict__ h1, float* __restrict__ t)
{
  int i = blockIdx.x * 256 + threadIdx.x;  // B*640
  if (i >= B_ * 640) return;
  int b = i / 640, j = i % 640;
  t[i] = (j < E_) ? emb[(size_t)maxid[b] * E_ + j] : h1[b * H_ + (j - E_)];
}

__global__ __launch_bounds__(64) void rate_head(const float* __restrict__ rate_in,
                                                const float* __restrict__ rate_w,
                                                const float* __restrict__ rate_b,
                                                float* __restrict__ out)
{
  int b = blockIdx.x, t = threadIdx.x;
  float s = 0.f;
  #pragma unroll
  for (int i = 0; i < 8; i++) s += rate_in[b * H_ + t + 64 * i] * rate_w[t + 64 * i];
  #pragma unroll
  for (int m = 32; m; m >>= 1) s += __shfl_xor(s, m);
  if (t == 0) out[b] = sigmoidf(s + rate_b[0]);
}

// ---------------------------------------------------------------------------
extern "C" void kernel_launch(void* const* d_in, const int* in_sizes, int n_in,
                              void* d_out, int out_size, void* d_ws, size_t ws_size,
                              hipStream_t stream)
{
  const int*   input_id   = (const int*)  d_in[0];
  const float* input_rate = (const float*)d_in[1];
  const float* hidden     = (const float*)d_in[2];   // h0 (B,H)
  const float* enc        = (const float*)d_in[3];   // (S,B,H)
  const int*   attn_mask  = (const int*)  d_in[4];
  const float* cv         = (const float*)d_in[5];
  const float* emb        = (const float*)d_in[6];
  const float* attn_w     = (const float*)d_in[7];
  const float* attn_b     = (const float*)d_in[8];
  const float* v_w        = (const float*)d_in[9];
  const float* w_ih       = (const float*)d_in[10];
  const float* w_hh       = (const float*)d_in[11];
  const float* b_ih       = (const float*)d_in[12];
  const float* b_hh       = (const float*)d_in[13];
  const float* fc_w       = (const float*)d_in[14];
  const float* fc_b       = (const float*)d_in[15];
  const float* tan_w      = (const float*)d_in[16];
  const float* tan_b      = (const float*)d_in[17];
  const float* rate_w     = (const float*)d_in[18];
  const float* rate_b     = (const float*)d_in[19];

  float* out = (float*)d_out;
  float* ws  = (float*)d_ws;
  float* hid_pb   = ws;                 // B*H     = 131072
  float* scores   = ws + 131072;        // B*S
  float* aw       = ws + 262144;        // B*S
  float* weighted = ws + 393216;        // B*H
  float* xbuf     = ws + 524288;        // B*641 (reused for tandem input B*640)
  float* gi       = ws + 688384;        // B*1536
  float* gh       = ws + 1081600;       // B*1536
  float* h1       = ws + 1474816;       // B*H
  float* rate_in  = ws + 1605888;       // B*H
  float* rowmax   = ws + 1736960;       // B
  float* Zrow     = ws + 1737216;       // B
  int*   maxid    = (int*)(ws + 1737472);

  float* out_pred = out;                             // (B,V)
  float* out_rate = out + (size_t)B_ * V_;           // (B,1)
  float* out_h1   = out + (size_t)B_ * V_ + B_;      // (B,H)

  hipMemsetAsync(scores, 0, (size_t)B_ * S_ * sizeof(float), stream);

  // hid_pb = h0 @ attn_w[:H] + attn_b   (fold attn_b in here)
  gemm_f32<false, false><<<dim3(4, 8), 256, 0, stream>>>(hidden, attn_w, attn_b, hid_pb, B_, H_, H_);

  // scores[b,s] = sum_k tanh(hid_pb + enc@attn_w[H:]) * v_w   (fused, atomic)
  attn_gemm_score<<<dim3(2, 2048), 256, 0, stream>>>(enc, attn_w + (size_t)H_ * H_, hid_pb, v_w, scores);

  attn_softmax<<<B_, 256, 0, stream>>>(scores, attn_mask, aw);
  attn_weighted<<<B_, 512, 0, stream>>>(aw, enc, weighted);
  build_x<<<641, 256, 0, stream>>>(weighted, input_id, emb, input_rate, xbuf);

  gemm_f32<true, false><<<dim3(4, 24), 256, 0, stream>>>(xbuf, w_ih, b_ih, gi, B_, 1536, RNNIN_);
  gemm_f32<true, false><<<dim3(4, 24), 256, 0, stream>>>(hidden, w_hh, b_hh, gh, B_, 1536, H_);
  gru_gates<<<512, 256, 0, stream>>>(gi, gh, hidden, h1, out_h1);

  logits_gemm<<<469, 256, 0, stream>>>(h1, fc_w, fc_b, out_pred);
  row_max<<<B_, 256, 0, stream>>>(out_pred, rowmax);
  exp_cv_sum<<<B_, 256, 0, stream>>>(out_pred, cv, rowmax, Zrow);
  norm_log<<<dim3(118, B_), 256, 0, stream>>>(out_pred, Zrow);
  row_argmax<<<B_, 256, 0, stream>>>(out_pred, maxid);

  build_tandem<<<640, 256, 0, stream>>>(maxid, emb, h1, xbuf);
  gemm_f32<false, true><<<dim3(4, 8), 256, 0, stream>>>(xbuf, tan_w, tan_b, rate_in, B_, H_, 640);
  rate_head<<<B_, 64, 0, stream>>>(rate_in, rate_w, rate_b, out_rate);
}

// Round 3
// 1172.191 us; speedup vs baseline: 1.3581x; 1.3581x over previous
//
#include <hip/hip_runtime.h>
#include <hip/hip_bf16.h>

#define B_ 256
#define S_ 512
#define H_ 512
#define E_ 128
#define V_ 30000
#define RNNIN_ 641

using bf16x8 = __attribute__((ext_vector_type(8))) short;
using f32x4  = __attribute__((ext_vector_type(4))) float;

__device__ __forceinline__ short f2bf(float f) {
  unsigned int u = __float_as_uint(f);
  u += 0x7fffu + ((u >> 16) & 1u);
  return (short)(u >> 16);
}

__device__ __forceinline__ float fast_tanh(float x) {
  x = fminf(10.f, fmaxf(-10.f, x));
  float t = __expf(2.f * x);
  return (t - 1.f) / (t + 1.f);
}

__device__ __forceinline__ float sigmoidf(float x) {
  return 1.f / (1.f + __expf(-x));
}

// ---------------------------------------------------------------------------
// Transpose + fp32->bf16: in (K,N) fp32 row-major -> out (N,K) bf16 row-major.
// Used ONLY for attn_w[H:] (512x512, tiny).
// ---------------------------------------------------------------------------
__global__ __launch_bounds__(256) void transpose_cvt(
    const float* __restrict__ in, unsigned short* __restrict__ out, int K, int N)
{
  __shared__ unsigned short tile[32][33];
  int n0 = blockIdx.x * 32, k0 = blockIdx.y * 32;
  int tx = threadIdx.x, ty = threadIdx.y;
  #pragma unroll
  for (int i = 0; i < 4; i++) {
    int k = k0 + ty + i * 8, n = n0 + tx;
    float v = (k < K && n < N) ? in[(size_t)k * N + n] : 0.f;
    tile[ty + i * 8][tx] = (unsigned short)f2bf(v);
  }
  __syncthreads();
  #pragma unroll
  for (int i = 0; i < 4; i++) {
    int n = n0 + ty + i * 8, k = k0 + tx;
    if (n < N && k < K) out[(size_t)n * K + k] = tile[tx][ty + i * 8];
  }
}

// ---------------------------------------------------------------------------
// Generic small fp32 GEMM (kept for the small matmuls — passed round 1).
// ---------------------------------------------------------------------------
template<bool BT, bool RELU>
__global__ __launch_bounds__(256) void gemm_f32(
    const float* __restrict__ A, const float* __restrict__ Bm,
    const float* __restrict__ bias, float* __restrict__ C,
    int M, int N, int K)
{
  __shared__ float As[16][65];
  __shared__ float Bs[16][65];
  const int m0 = blockIdx.x * 64, n0 = blockIdx.y * 64;
  const int tid = threadIdx.x;
  const int tx = tid & 15, ty = tid >> 4;
  float acc[4][4] = {};
  for (int k0 = 0; k0 < K; k0 += 16) {
    __syncthreads();
    #pragma unroll
    for (int i = 0; i < 4; i++) {
      int e = tid + i * 256;
      int m = e >> 4, k = e & 15;
      float v = 0.f;
      if (m0 + m < M && k0 + k < K) v = A[(size_t)(m0 + m) * K + k0 + k];
      As[k][m] = v;
    }
    #pragma unroll
    for (int i = 0; i < 4; i++) {
      int e = tid + i * 256;
      if (BT) {
        int n = e >> 4, k = e & 15;
        float v = 0.f;
        if (n0 + n < N && k0 + k < K) v = Bm[(size_t)(n0 + n) * K + k0 + k];
        Bs[k][n] = v;
      } else {
        int k = e >> 6, n = e & 63;
        float v = 0.f;
        if (n0 + n < N && k0 + k < K) v = Bm[(size_t)(k0 + k) * N + n0 + n];
        Bs[k][n] = v;
      }
    }
    __syncthreads();
    #pragma unroll
    for (int k = 0; k < 16; k++) {
      float a[4], b[4];
      #pragma unroll
      for (int i = 0; i < 4; i++) a[i] = As[k][ty * 4 + i];
      #pragma unroll
      for (int j = 0; j < 4; j++) b[j] = Bs[k][tx * 4 + j];
      #pragma unroll
      for (int i = 0; i < 4; i++)
        #pragma unroll
        for (int j = 0; j < 4; j++) acc[i][j] += a[i] * b[j];
    }
  }
  #pragma unroll
  for (int i = 0; i < 4; i++) {
    int m = m0 + ty * 4 + i;
    if (m >= M) continue;
    #pragma unroll
    for (int j = 0; j < 4; j++) {
      int n = n0 + tx * 4 + j;
      if (n >= N) continue;
      float v = acc[i][j] + (bias ? bias[n] : 0.f);
      if (RELU) v = fmaxf(v, 0.f);
      C[(size_t)m * N + n] = v;
    }
  }
}

// ---------------------------------------------------------------------------
// Attention GEMM fused with tanh(.)·v_w reduction into scores.
// A = enc (S*B, H) fp32.  Bt = attn_w[H:] pre-transposed bf16 (n,k).
// Tile 64m x 512n (full N), BK=32, 512 threads. Fragment-major LDS:
// lane l's 16B fragment at base + l*16 -> conflict-free b128 reads.
// ---------------------------------------------------------------------------
__global__ __launch_bounds__(512, 4) void attn_gemm_score(
    const float* __restrict__ A, const unsigned short* __restrict__ Bt,
    const float* __restrict__ hid_pb, const float* __restrict__ v_w,
    float* __restrict__ scores)
{
  __shared__ short As[4 * 64 * 8];        // [ti][lane][8]  = 4 KB
  __shared__ short Bs[8 * 4 * 64 * 8];    // [wv][tj][lane][8] = 32 KB
  const int m0 = blockIdx.x * 64;
  const int tid = threadIdx.x;
  const int lane = tid & 63;
  const int wv = tid >> 6;
  const int quad = lane >> 4, l15 = lane & 15;

  f32x4 acc[4][4];
  #pragma unroll
  for (int i = 0; i < 4; i++)
    #pragma unroll
    for (int j = 0; j < 4; j++) acc[i][j] = f32x4{0.f, 0.f, 0.f, 0.f};

  for (int kt = 0; kt < 16; kt++) {
    const int kb = kt * 32;
    __syncthreads();
    if (tid < 256) {
      int m = tid >> 2, q = tid & 3;
      const float* src = A + (size_t)(m0 + m) * H_ + kb + q * 8;
      float4 v0 = *(const float4*)src;
      float4 v1 = *(const float4*)(src + 4);
      bf16x8 pk;
      pk[0] = f2bf(v0.x); pk[1] = f2bf(v0.y); pk[2] = f2bf(v0.z); pk[3] = f2bf(v0.w);
      pk[4] = f2bf(v1.x); pk[5] = f2bf(v1.y); pk[6] = f2bf(v1.z); pk[7] = f2bf(v1.w);
      int ti = m >> 4, ld = q * 16 + (m & 15);
      *(bf16x8*)&As[(ti * 64 + ld) * 8] = pk;
    }
    #pragma unroll
    for (int p = 0; p < 4; p++) {
      int n = p * 128 + (tid >> 2), q = tid & 3;
      bf16x8 v = *(const bf16x8*)(Bt + (size_t)n * H_ + kb + q * 8);
      int wvd = n >> 6, tj = (n >> 4) & 3, ld = q * 16 + (n & 15);
      *(bf16x8*)&Bs[((wvd * 4 + tj) * 64 + ld) * 8] = v;
    }
    __syncthreads();
    bf16x8 a[4], b[4];
    #pragma unroll
    for (int ti = 0; ti < 4; ti++) a[ti] = *(const bf16x8*)&As[(ti * 64 + lane) * 8];
    #pragma unroll
    for (int tj = 0; tj < 4; tj++) b[tj] = *(const bf16x8*)&Bs[((wv * 4 + tj) * 64 + lane) * 8];
    #pragma unroll
    for (int ti = 0; ti < 4; ti++)
      #pragma unroll
      for (int tj = 0; tj < 4; tj++)
        acc[ti][tj] = __builtin_amdgcn_mfma_f32_16x16x32_bf16(a[ti], b[tj], acc[ti][tj], 0, 0, 0);
  }

  #pragma unroll
  for (int ti = 0; ti < 4; ti++) {
    #pragma unroll
    for (int r = 0; r < 4; r++) {
      int m = m0 + ti * 16 + quad * 4 + r;
      int b = m & (B_ - 1);
      int s = m >> 8;
      float sum = 0.f;
      #pragma unroll
      for (int tj = 0; tj < 4; tj++) {
        int n = wv * 64 + tj * 16 + l15;
        float v = acc[ti][tj][r] + hid_pb[b * H_ + n];
        sum += fast_tanh(v) * v_w[n];
      }
      sum += __shfl_xor(sum, 1);
      sum += __shfl_xor(sum, 2);
      sum += __shfl_xor(sum, 4);
      sum += __shfl_xor(sum, 8);
      if (l15 == 0) atomicAdd(scores + b * S_ + s, sum);
    }
  }
}

// ---------------------------------------------------------------------------
// Logits GEMM: C(256,30000) = h1 @ fc_id_w + b.
// A = h1b bf16 (B,H). Bw = fc_id_w fp32 (K=512, V) IN NATIVE LAYOUT:
// each thread loads a 16-k column strip for one n (wave = 64 consecutive n,
// fully coalesced), converts, writes two b128 fragments (4-way alias only).
// Tile 256m x 64n, BK=64, 256 threads. Fragment-major LDS.
// ---------------------------------------------------------------------------
__global__ __launch_bounds__(256, 4) void logits_gemm(
    const unsigned short* __restrict__ Ab, const float* __restrict__ Bw,
    const float* __restrict__ bias, float* __restrict__ C)
{
  __shared__ short As[2 * 16 * 64 * 8];   // [c][mt][lane][8] = 32 KB
  __shared__ short Bs[2 * 4 * 64 * 8];    // [c][tj][lane][8] = 8 KB
  const int n0 = blockIdx.x * 64;
  const int tid = threadIdx.x;
  const int lane = tid & 63;
  const int wv = tid >> 6;
  const int quad = lane >> 4, l15 = lane & 15;

  f32x4 acc[4][4];
  #pragma unroll
  for (int i = 0; i < 4; i++)
    #pragma unroll
    for (int j = 0; j < 4; j++) acc[i][j] = f32x4{0.f, 0.f, 0.f, 0.f};

  // B staging decode (loop-invariant)
  const int nB  = tid & 63;          // n within tile
  const int kg  = tid >> 6;          // 0..3 -> k range kg*16..+15
  const int cB  = kg >> 1;           // 32-k chunk
  const int q0  = (kg & 1) * 2;      // first q of the pair
  const int tjB = nB >> 4;
  const bool nOK = (n0 + nB) < V_;

  for (int kt = 0; kt < 8; kt++) {
    const int kb = kt * 64;
    __syncthreads();
    // stage A (bf16 copy, fragment-major)
    #pragma unroll
    for (int p = 0; p < 8; p++) {
      int m = p * 32 + (tid >> 3), f = tid & 7;
      int c = f >> 2, q = f & 3;
      bf16x8 v = *(const bf16x8*)(Ab + (size_t)m * H_ + kb + c * 32 + q * 8);
      int mt = m >> 4, ld = q * 16 + (m & 15);
      *(bf16x8*)&As[((c * 16 + mt) * 64 + ld) * 8] = v;
    }
    // stage B: 16 coalesced fp32 column loads -> two b128 fragment writes
    {
      float col[16];
      const float* src = Bw + (size_t)(kb + kg * 16) * V_ + n0 + nB;
      #pragma unroll
      for (int i = 0; i < 16; i++) col[i] = nOK ? src[(size_t)i * V_] : 0.f;
      bf16x8 f0, f1;
      #pragma unroll
      for (int i = 0; i < 8; i++) { f0[i] = f2bf(col[i]); f1[i] = f2bf(col[8 + i]); }
      int ld0 = q0 * 16 + (nB & 15);
      *(bf16x8*)&Bs[((cB * 4 + tjB) * 64 + ld0) * 8] = f0;
      *(bf16x8*)&Bs[((cB * 4 + tjB) * 64 + ld0 + 16) * 8] = f1;
    }
    __syncthreads();
    #pragma unroll
    for (int c = 0; c < 2; c++) {
      bf16x8 a[4], b[4];
      #pragma unroll
      for (int ti = 0; ti < 4; ti++)
        a[ti] = *(const bf16x8*)&As[((c * 16 + wv * 4 + ti) * 64 + lane) * 8];
      #pragma unroll
      for (int tj = 0; tj < 4; tj++)
        b[tj] = *(const bf16x8*)&Bs[((c * 4 + tj) * 64 + lane) * 8];
      #pragma unroll
      for (int ti = 0; ti < 4; ti++)
        #pragma unroll
        for (int tj = 0; tj < 4; tj++)
          acc[ti][tj] = __builtin_amdgcn_mfma_f32_16x16x32_bf16(a[ti], b[tj], acc[ti][tj], 0, 0, 0);
    }
  }
  #pragma unroll
  for (int ti = 0; ti < 4; ti++)
    #pragma unroll
    for (int r = 0; r < 4; r++) {
      int m = wv * 64 + ti * 16 + quad * 4 + r;
      #pragma unroll
      for (int tj = 0; tj < 4; tj++) {
        int n = n0 + tj * 16 + l15;
        if (n < V_) C[(size_t)m * V_ + n] = acc[ti][tj][r] + bias[n];
      }
    }
}

// --------------------------- small kernels ---------------------------------
__global__ __launch_bounds__(256) void attn_softmax(
    const float* __restrict__ scores, const int* __restrict__ mask, float* __restrict__ aw)
{
  int b = blockIdx.x, tid = threadIdx.x;
  __shared__ float red[256];
  float v0 = scores[b * S_ + tid];
  float v1 = scores[b * S_ + tid + 256];
  if (mask[b * S_ + tid] == 0) v0 = -1e10f;
  if (mask[b * S_ + tid + 256] == 0) v1 = -1e10f;
  red[tid] = fmaxf(v0, v1);
  __syncthreads();
  for (int off = 128; off; off >>= 1) { if (tid < off) red[tid] = fmaxf(red[tid], red[tid + off]); __syncthreads(); }
  float mx = red[0];
  __syncthreads();
  float e0 = __expf(v0 - mx), e1 = __expf(v1 - mx);
  red[tid] = e0 + e1;
  __syncthreads();
  for (int off = 128; off; off >>= 1) { if (tid < off) red[tid] += red[tid + off]; __syncthreads(); }
  float inv = 1.f / red[0];
  aw[b * S_ + tid] = e0 * inv;
  aw[b * S_ + tid + 256] = e1 * inv;
}

__global__ __launch_bounds__(512) void attn_weighted(
    const float* __restrict__ aw, const float* __restrict__ enc, float* __restrict__ weighted)
{
  int b = blockIdx.x, h = threadIdx.x;
  __shared__ float a_s[S_];
  a_s[h] = aw[b * S_ + h];
  __syncthreads();
  float acc = 0.f;
  #pragma unroll 8
  for (int s = 0; s < S_; s++)
    acc += a_s[s] * enc[((size_t)s * B_ + b) * H_ + h];
  weighted[b * H_ + h] = acc;
}

__global__ void build_x(const float* __restrict__ weighted, const int* __restrict__ ids,
                        const float* __restrict__ emb, const float* __restrict__ rate,
                        float* __restrict__ x)
{
  int i = blockIdx.x * 256 + threadIdx.x;
  if (i >= B_ * RNNIN_) return;
  int b = i / RNNIN_, j = i % RNNIN_;
  float v;
  if (j < H_) v = weighted[b * H_ + j];
  else if (j < H_ + E_) v = emb[(size_t)ids[b] * E_ + (j - H_)];
  else v = rate[b];
  x[i] = v;
}

__global__ void gru_gates(const float* __restrict__ gi, const float* __restrict__ gh,
                          const float* __restrict__ h0, float* __restrict__ h1,
                          unsigned short* __restrict__ h1b, float* __restrict__ h1_out)
{
  int i = blockIdx.x * 256 + threadIdx.x;  // B*H
  int b = i >> 9, j = i & (H_ - 1);
  const float* gib = gi + (size_t)b * 1536;
  const float* ghb = gh + (size_t)b * 1536;
  float r = sigmoidf(gib[j] + ghb[j]);
  float z = sigmoidf(gib[512 + j] + ghb[512 + j]);
  float n = fast_tanh(gib[1024 + j] + r * ghb[1024 + j]);
  float h = (1.f - z) * n + z * h0[i];
  h1[i] = h;
  h1b[i] = (unsigned short)f2bf(h);
  h1_out[i] = h;
}

// Fused row_max + exp*cv + sum + argmax + normalize/log. In-place on lp.
__global__ __launch_bounds__(1024) void softmax_fused(
    float* __restrict__ lp, const float* __restrict__ cv, int* __restrict__ maxid)
{
  int b = blockIdx.x, tid = threadIdx.x;
  int wid = tid >> 6, lane = tid & 63;
  float* row = lp + (size_t)b * V_;
  const float* cvr = cv + (size_t)b * V_;
  __shared__ float redf[16];
  __shared__ float rede[16];
  __shared__ int   redi[16];

  float mx = -INFINITY;
  for (int v = tid; v < V_; v += 1024) mx = fmaxf(mx, row[v]);
  #pragma unroll
  for (int o = 1; o < 64; o <<= 1) mx = fmaxf(mx, __shfl_xor(mx, o));
  if (lane == 0) redf[wid] = mx;
  __syncthreads();
  if (tid == 0) {
    float m = redf[0];
    for (int i = 1; i < 16; i++) m = fmaxf(m, redf[i]);
    redf[0] = m;
  }
  __syncthreads();
  float M = redf[0];
  __syncthreads();

  float s = 0.f, best = -1.f;
  int bi = 0;
  for (int v = tid; v < V_; v += 1024) {
    float e = __expf(row[v] - M) * cvr[v];
    row[v] = e;
    s += e;
    if (e > best) { best = e; bi = v; }
  }
  #pragma unroll
  for (int o = 1; o < 64; o <<= 1) {
    s += __shfl_xor(s, o);
    float ob = __shfl_xor(best, o);
    int oi = __shfl_xor(bi, o);
    if (ob > best || (ob == best && oi < bi)) { best = ob; bi = oi; }
  }
  if (lane == 0) { redf[wid] = s; rede[wid] = best; redi[wid] = bi; }
  __syncthreads();
  if (tid == 0) {
    float ss = 0.f, bb = rede[0];
    int ii = redi[0];
    for (int i = 0; i < 16; i++) {
      ss += redf[i];
      if (rede[i] > bb || (rede[i] == bb && redi[i] < ii)) { bb = rede[i]; ii = redi[i]; }
    }
    redf[0] = ss;
    maxid[b] = ii;
  }
  __syncthreads();
  float inv = 1.f / redf[0];
  for (int v = tid; v < V_; v += 1024) {
    float p = row[v] * inv;
    p = fminf(fmaxf(p, 1e-6f), 1.f);
    row[v] = __logf(p);
  }
}

__global__ void build_tandem(const int* __restrict__ maxid, const float* __restrict__ emb,
                             const float* __restrict__ h1, float* __restrict__ t)
{
  int i = blockIdx.x * 256 + threadIdx.x;  // B*640
  if (i >= B_ * 640) return;
  int b = i / 640, j = i % 640;
  t[i] = (j < E_) ? emb[(size_t)maxid[b] * E_ + j] : h1[b * H_ + (j - E_)];
}

__global__ __launch_bounds__(64) void rate_head(const float* __restrict__ rate_in,
                                                const float* __restrict__ rate_w,
                                                const float* __restrict__ rate_b,
                                                float* __restrict__ out)
{
  int b = blockIdx.x, t = threadIdx.x;
  float s = 0.f;
  #pragma unroll
  for (int i = 0; i < 8; i++) s += rate_in[b * H_ + t + 64 * i] * rate_w[t + 64 * i];
  #pragma unroll
  for (int m = 32; m; m >>= 1) s += __shfl_xor(s, m);
  if (t == 0) out[b] = sigmoidf(s + rate_b[0]);
}

// ---------------------------------------------------------------------------
extern "C" void kernel_launch(void* const* d_in, const int* in_sizes, int n_in,
                              void* d_out, int out_size, void* d_ws, size_t ws_size,
                              hipStream_t stream)
{
  const int*   input_id   = (const int*)  d_in[0];
  const float* input_rate = (const float*)d_in[1];
  const float* hidden     = (const float*)d_in[2];
  const float* enc        = (const float*)d_in[3];
  const int*   attn_mask  = (const int*)  d_in[4];
  const float* cv         = (const float*)d_in[5];
  const float* emb        = (const float*)d_in[6];
  const float* attn_w     = (const float*)d_in[7];
  const float* attn_b     = (const float*)d_in[8];
  const float* v_w        = (const float*)d_in[9];
  const float* w_ih       = (const float*)d_in[10];
  const float* w_hh       = (const float*)d_in[11];
  const float* b_ih       = (const float*)d_in[12];
  const float* b_hh       = (const float*)d_in[13];
  const float* fc_w       = (const float*)d_in[14];
  const float* fc_b       = (const float*)d_in[15];
  const float* tan_w      = (const float*)d_in[16];
  const float* tan_b      = (const float*)d_in[17];
  const float* rate_w     = (const float*)d_in[18];
  const float* rate_b     = (const float*)d_in[19];

  float* out = (float*)d_out;
  float* ws  = (float*)d_ws;
  // ws layout (float offsets), carefully non-overlapping; total 1,933,824 floats = 7.74 MB
  float* hid_pb   = ws;                   // [0,       131072)
  float* scores   = ws + 131072;          // [131072,  262144)
  float* aw       = ws + 262144;          // [262144,  393216)
  float* weighted = ws + 393216;          // [393216,  524288)
  float* xbuf     = ws + 524288;          // [524288,  688384)  B*641
  float* gi       = ws + 688384;          // [688384, 1081600)  B*1536
  float* gh       = ws + 1081600;         // [1081600,1474816)  B*1536
  float* h1       = ws + 1474816;         // [1474816,1605888)  B*H
  float* rate_in  = ws + 1605888;         // [1605888,1736960)  B*H
  int*   maxid    = (int*)(ws + 1736960); // [1736960,1737216)  B ints
  unsigned short* Bt  = (unsigned short*)(ws + 1737216); // 512*512 bf16 = 131072 floats -> [1737216,1868288)
  unsigned short* h1b = (unsigned short*)(ws + 1868288); // 256*512 bf16 = 65536 floats  -> [1868288,1933824)

  float* out_pred = out;
  float* out_rate = out + (size_t)B_ * V_;
  float* out_h1   = out + (size_t)B_ * V_ + B_;

  transpose_cvt<<<dim3(16, 16), dim3(32, 8), 0, stream>>>(attn_w + (size_t)H_ * H_, Bt, H_, H_);

  hipMemsetAsync(scores, 0, (size_t)B_ * S_ * sizeof(float), stream);

  gemm_f32<false, false><<<dim3(4, 8), 256, 0, stream>>>(hidden, attn_w, attn_b, hid_pb, B_, H_, H_);

  attn_gemm_score<<<2048, 512, 0, stream>>>(enc, Bt, hid_pb, v_w, scores);

  attn_softmax<<<B_, 256, 0, stream>>>(scores, attn_mask, aw);
  attn_weighted<<<B_, 512, 0, stream>>>(aw, enc, weighted);
  build_x<<<641, 256, 0, stream>>>(weighted, input_id, emb, input_rate, xbuf);

  gemm_f32<true, false><<<dim3(4, 24), 256, 0, stream>>>(xbuf, w_ih, b_ih, gi, B_, 1536, RNNIN_);
  gemm_f32<true, false><<<dim3(4, 24), 256, 0, stream>>>(hidden, w_hh, b_hh, gh, B_, 1536, H_);
  gru_gates<<<512, 256, 0, stream>>>(gi, gh, hidden, h1, h1b, out_h1);

  logits_gemm<<<469, 256, 0, stream>>>(h1b, fc_w, fc_b, out_pred);
  softmax_fused<<<B_, 1024, 0, stream>>>(out_pred, cv, maxid);

  build_tandem<<<640, 256, 0, stream>>>(maxid, emb, h1, xbuf);
  gemm_f32<false, true><<<dim3(4, 8), 256, 0, stream>>>(xbuf, tan_w, tan_b, rate_in, B_, H_, 640);
  rate_head<<<B_, 64, 0, stream>>>(rate_in, rate_w, rate_b, out_rate);
}